// Round 11
// baseline (2601.897 us; speedup 1.0000x reference)
//
#include <hip/hip_runtime.h>
#include <cstdint>

#define NPTS 2048
#define BATCH 8
#define KNN 40

__device__ __forceinline__ float lrelu(float v){ return fmaxf(v, 0.2f*v); }
__device__ __forceinline__ bool better(float v1,int i1,float v2,int i2){
  return (v1>v2) || (v1==v2 && i1<i2);
}
__device__ __forceinline__ float4 ld4(const float* p){ return *(const float4*)p; }

// insert (d,m) into sorted-desc 8-list if it beats the tail; static CE chain.
#define INSERT8(v,id,d,m) \
  if (better(d, m, v[7], id[7])){ \
    v[7]=d; id[7]=m; \
    { if (better(v[7],id[7],v[6],id[6])){ float tv=v[6];int ti=id[6]; v[6]=v[7];id[6]=id[7]; v[7]=tv;id[7]=ti; } } \
    { if (better(v[6],id[6],v[5],id[5])){ float tv=v[5];int ti=id[5]; v[5]=v[6];id[5]=id[6]; v[6]=tv;id[6]=ti; } } \
    { if (better(v[5],id[5],v[4],id[4])){ float tv=v[4];int ti=id[4]; v[4]=v[5];id[4]=id[5]; v[5]=tv;id[5]=ti; } } \
    { if (better(v[4],id[4],v[3],id[3])){ float tv=v[3];int ti=id[3]; v[3]=v[4];id[3]=id[4]; v[4]=tv;id[4]=ti; } } \
    { if (better(v[3],id[3],v[2],id[2])){ float tv=v[2];int ti=id[2]; v[2]=v[3];id[2]=id[3]; v[3]=tv;id[3]=ti; } } \
    { if (better(v[2],id[2],v[1],id[1])){ float tv=v[1];int ti=id[1]; v[1]=v[2];id[1]=id[2]; v[2]=tv;id[2]=ti; } } \
    { if (better(v[1],id[1],v[0],id[0])){ float tv=v[0];int ti=id[0]; v[0]=v[1];id[0]=id[1]; v[1]=tv;id[1]=ti; } } \
  }

// ---------------- generic transpose: dst[c*R+r] = src[r*ld+off+c] ----------------
__global__ void transpose_kernel(const float* __restrict__ src, float* __restrict__ dst,
                                 int R, int C, int ld, int off){
  int i = blockIdx.x*256 + threadIdx.x;
  if (i < R*C){ int r = i / C, c = i % C; dst[c*R + r] = src[r*ld + off + c]; }
}

// ---------------- squared norms, rows layout (B,3,N) ----------------
template<int TAG>
__global__ void norms_rows_kernel(const float* __restrict__ x, float* __restrict__ xx, int N){
  int b = blockIdx.y; int n = blockIdx.x*256 + threadIdx.x;
  const float* xb = x + (size_t)b*3*N;
  float v0 = xb[n], v1 = xb[N+n], v2 = xb[2*N+n];
  xx[(size_t)b*N + n] = v0*v0 + v1*v1 + v2*v2;
}

// ---------------- squared norms, channel-last 64ch slice of (B,N,192) ----------------
template<int TAG>
__global__ void norms_cl_kernel(const float* __restrict__ f, int off, float* __restrict__ xx, int N){
  int b = blockIdx.y; int n = blockIdx.x*256 + threadIdx.x;
  const float4* p = (const float4*)(f + ((size_t)b*N + n)*192 + off);
  float s = 0.f;
#pragma unroll
  for (int q=0;q<16;q++){ float4 v = p[q]; s += v.x*v.x + v.y*v.y + v.z*v.z + v.w*v.w; }
  xx[(size_t)b*N + n] = s;
}

// ---------------- knn 3-channel: 4 queries/block (1/wave), zero LDS, zero barriers ----------------
// Insertion top-8 during dist; 40-round butterfly extraction; rare refill recomputes.
template<int TAG>
__global__ __launch_bounds__(256) void knn3_kernel(
    const float* __restrict__ xrows, const float* __restrict__ xx,
    int* __restrict__ idxT, int N){
  const int b = blockIdx.y, tid = threadIdx.x;
  const int w = tid>>6, lane = tid&63;
  const int nq = blockIdx.x*4 + w;
  const float* xb = xrows + (size_t)b*3*N;
  const float* xxb = xx + (size_t)b*N;
  float c0 = xb[nq], c1 = xb[N+nq], c2 = xb[2*N+nq];
  float xxn = xxb[nq];
  float v[8]; int id[8];
#pragma unroll
  for (int j=0;j<8;j++){ v[j]=-__builtin_inff(); id[j]=0x7FFFFFFF; }
  for (int j=0;j<32;j++){
    int m = j*64 + lane;
    float s = c0*xb[m] + c1*xb[N+m] + c2*xb[2*N+m];
    float d = 2.f*s - xxn - xxb[m];
    INSERT8(v, id, d, m)
  }
  float lastv = 0.f; int lasti = 0;
  int win = 0;
  for (int r=0;r<KNN;r++){
    float bv = v[0]; int bi = id[0];
#pragma unroll
    for (int off=32; off; off>>=1){
      float ov = __shfl_xor(bv, off);
      int   oi = __shfl_xor(bi, off);
      if (better(ov, oi, bv, bi)){ bv = ov; bi = oi; }
    }
    if (lane == r) win = bi;
    if (id[0] == bi){
      lastv = v[0]; lasti = id[0];
#pragma unroll
      for (int j=0;j<7;j++){ v[j]=v[j+1]; id[j]=id[j+1]; }
      v[7] = -__builtin_inff(); id[7] = 0x7FFFFFFF;
      if (id[0] == 0x7FFFFFFF){   // rare refill: best strictly worse than last pop
        float nv = -__builtin_inff(); int ni = 0x7FFFFFFF;
        for (int j=0;j<32;j++){
          int m = j*64 + lane;
          float s = c0*xb[m] + c1*xb[N+m] + c2*xb[2*N+m];
          float dd = 2.f*s - xxn - xxb[m];
          if (better(lastv, lasti, dd, m) && better(dd, m, nv, ni)){ nv=dd; ni=m; }
        }
        v[0] = nv; id[0] = ni;
      }
    }
  }
  if (lane < KNN) idxT[((size_t)b*KNN + lane)*N + nq] = win;
}

// ---------------- knn 64-channel (channel-last), 4 queries/block ----------------
// v5: cand tile in LDS only (16 KB); insertion top-8 during dist (no dist array);
// wave-private extraction; rare refill recomputes from global.
template<int TAG>
__global__ __launch_bounds__(256) void knn64_kernel(
    const float* __restrict__ featT, int featOff,
    const float* __restrict__ xx, int* __restrict__ idxT, int N){
  const int b = blockIdx.y, tid = threadIdx.x;
  const int w = tid>>6, lane = tid&63;
  __shared__ float cand[64*64];    // xor-swizzled [cand][ch] tile, block-shared
  const float* fb = featT + featOff;
  const float* xxb = xx + (size_t)b*N;
  const int nq = blockIdx.x*4 + w;
  float4 ctr[16];
  {
    const float4* cp = (const float4*)(fb + ((size_t)b*N + nq)*192);
#pragma unroll
    for (int q=0;q<16;q++) ctr[q] = cp[q];
  }
  float xxn = xxb[nq];
  float v[8]; int id[8];
#pragma unroll
  for (int j=0;j<8;j++){ v[j]=-__builtin_inff(); id[j]=0x7FFFFFFF; }
  float4 g[4];
#pragma unroll
  for (int r=0;r<4;r++){
    int k2 = tid + 256*r;
    int c = k2>>4, f = k2&15;
    g[r] = ld4(&fb[((size_t)b*N + c)*192 + 4*f]);
  }
  for (int t=0;t<32;t++){
    __syncthreads();                 // prev compute done reading cand
#pragma unroll
    for (int r=0;r<4;r++){
      int k2 = tid + 256*r;
      int c = k2>>4, f = k2&15;
      *(float4*)&cand[(c<<6) + ((f ^ (c&15))<<2)] = g[r];
    }
    __syncthreads();
    if (t+1 < 32){                   // issue next tile's loads; latency overlaps compute
      int m0n = (t+1)*64;
#pragma unroll
      for (int r=0;r<4;r++){
        int k2 = tid + 256*r;
        int c = k2>>4, f = k2&15;
        g[r] = ld4(&fb[((size_t)b*N + m0n + c)*192 + 4*f]);
      }
    }
    float s0=0.f,s1=0.f,s2=0.f,s3=0.f;
#pragma unroll
    for (int u=0;u<16;u++){
      float4 mv = *(const float4*)&cand[(lane<<6) + ((u ^ (lane&15))<<2)];
      s0 = fmaf(ctr[u].x, mv.x, s0);
      s1 = fmaf(ctr[u].y, mv.y, s1);
      s2 = fmaf(ctr[u].z, mv.z, s2);
      s3 = fmaf(ctr[u].w, mv.w, s3);
    }
    int m = t*64 + lane;
    float d = 2.f*((s0+s1)+(s2+s3)) - xxn - xxb[m];
    INSERT8(v, id, d, m)
  }
  // ---- 40 extraction rounds: butterfly + pop-shift; zero barriers/LDS ----
  float lastv = 0.f; int lasti = 0;
  int win = 0;
  for (int r=0;r<KNN;r++){
    float bv = v[0]; int bi = id[0];
#pragma unroll
    for (int off=32; off; off>>=1){
      float ov = __shfl_xor(bv, off);
      int   oi = __shfl_xor(bi, off);
      if (better(ov, oi, bv, bi)){ bv = ov; bi = oi; }
    }
    if (lane == r) win = bi;
    if (id[0] == bi){                // unique owner (indices unique)
      lastv = v[0]; lasti = id[0];
#pragma unroll
      for (int j=0;j<7;j++){ v[j]=v[j+1]; id[j]=id[j+1]; }
      v[7] = -__builtin_inff(); id[7] = 0x7FFFFFFF;
      if (id[0] == 0x7FFFFFFF){      // rare: lane contributed >8 of top-40 -> refill head
        float nv = -__builtin_inff(); int ni = 0x7FFFFFFF;
        for (int j=0;j<32;j++){
          int m = j*64 + lane;
          const float4* mp = (const float4*)(fb + ((size_t)b*N + m)*192);
          float t0=0.f,t1=0.f,t2=0.f,t3=0.f;
#pragma unroll
          for (int u=0;u<16;u++){
            float4 mv = mp[u];
            t0 = fmaf(ctr[u].x, mv.x, t0);
            t1 = fmaf(ctr[u].y, mv.y, t1);
            t2 = fmaf(ctr[u].z, mv.z, t2);
            t3 = fmaf(ctr[u].w, mv.w, t3);
          }
          float dd = 2.f*((t0+t1)+(t2+t3)) - xxn - xxb[m];
          if (better(lastv, lasti, dd, m) && better(dd, m, nv, ni)){ nv=dd; ni=m; }
        }
        v[0] = nv; id[0] = ni;
      }
    }
  }
  if (lane < KNN) idxT[((size_t)b*KNN + lane)*N + nq] = win;
}

// ==================== register-tiled edge kernels ====================

// ---- edgeA (t-path): 3ch -> 64 -> 128, max over k ----
// v2: 4 waves x 16 points; stage2 tiled as 4 panels o=p*32+oq*4 (conflict-free w2T reads).
__global__ __launch_bounds__(256) void edgeA_kernel(
    const float* __restrict__ x, const int* __restrict__ idxT,
    const float* __restrict__ w1, const float* __restrict__ w2,
    float* __restrict__ tT, int N){
  __shared__ float w1aT[3*64];
  __shared__ float wd3T[3*64];
  __shared__ float w2T[64*128];      // [c][o]; reused as merge buffer (4 x 16r x 128o)
  __shared__ float aT3[4][3*16];
  __shared__ float s1T[4][64*16];    // [c][r]
  const int tid = threadIdx.x, w = tid>>6, lane = tid&63;
  const int oq = lane&7, rg = lane>>3;
  const int o0 = oq*8, r0 = rg*2;
  const int b = blockIdx.y, n0 = blockIdx.x*16;
  for (int i=tid; i<192; i+=256){
    int o = i&63, c = i/64;
    float a = w1[o*6+c];
    w1aT[c*64+o] = a; wd3T[c*64+o] = w1[o*6+3+c] - a;
  }
  for (int i=tid; i<128*64; i+=256){
    int o = i>>6, c = i&63;
    w2T[c*128+o] = w2[o*64+c];
  }
  if (tid < 48){ int c = tid>>4, r = tid&15; aT3[0][c*16+r] = x[((size_t)b*3+c)*N + n0 + r]; }
  __syncthreads();
  float base[16];
#pragma unroll
  for (int i=0;i<16;i++) base[i]=0.f;
#pragma unroll
  for (int c=0;c<3;c++){
    float4 wA = ld4(&wd3T[c*64+o0]), wB = ld4(&wd3T[c*64+o0+4]);
    float2 av = *(const float2*)&aT3[0][c*16+r0];
    float wv[8] = {wA.x,wA.y,wA.z,wA.w,wB.x,wB.y,wB.z,wB.w};
    float rv[2] = {av.x,av.y};
#pragma unroll
    for (int oo=0;oo<8;oo++)
#pragma unroll
      for (int rr=0;rr<2;rr++) base[oo*2+rr] = fmaf(wv[oo], rv[rr], base[oo*2+rr]);
  }
  __syncthreads();   // all waves done reading aT3[0] before k-loop overwrites
  float mx[32];
#pragma unroll
  for (int i=0;i<32;i++) mx[i] = -__builtin_inff();
  for (int it=0; it<10; it++){
    int k = it*4 + w;
    int m = idxT[((size_t)b*KNN + k)*N + n0 + (lane&15)];
    if (lane < 48){ int c = lane>>4; aT3[w][c*16 + (lane&15)] = x[((size_t)b*3+c)*N + m]; }
    // stage1 (64 o x 16 r)
    float acc[16];
#pragma unroll
    for (int i=0;i<16;i++) acc[i] = base[i];
#pragma unroll
    for (int c=0;c<3;c++){
      float4 wA = ld4(&w1aT[c*64+o0]), wB = ld4(&w1aT[c*64+o0+4]);
      float2 av = *(const float2*)&aT3[w][c*16+r0];
      float wv[8] = {wA.x,wA.y,wA.z,wA.w,wB.x,wB.y,wB.z,wB.w};
      float rv[2] = {av.x,av.y};
#pragma unroll
      for (int oo=0;oo<8;oo++)
#pragma unroll
        for (int rr=0;rr<2;rr++) acc[oo*2+rr] = fmaf(wv[oo], rv[rr], acc[oo*2+rr]);
    }
#pragma unroll
    for (int oo=0;oo<8;oo++){
      float2 sv; sv.x = lrelu(acc[oo*2]); sv.y = lrelu(acc[oo*2+1]);
      *(float2*)&s1T[w][(o0+oo)*16 + r0] = sv;
    }
    // stage2 (128 o x 16 r): 4 panels, o = p*32 + oq*4 -> 32 banks, conflict-free
    float acc2[32];
#pragma unroll
    for (int i=0;i<32;i++) acc2[i]=0.f;
    for (int c=0;c<64;c++){
      float2 av = *(const float2*)&s1T[w][c*16 + r0];
#pragma unroll
      for (int p=0;p<4;p++){
        float4 wv = ld4(&w2T[c*128 + p*32 + oq*4]);
        acc2[p*8+0] = fmaf(wv.x, av.x, acc2[p*8+0]);
        acc2[p*8+1] = fmaf(wv.x, av.y, acc2[p*8+1]);
        acc2[p*8+2] = fmaf(wv.y, av.x, acc2[p*8+2]);
        acc2[p*8+3] = fmaf(wv.y, av.y, acc2[p*8+3]);
        acc2[p*8+4] = fmaf(wv.z, av.x, acc2[p*8+4]);
        acc2[p*8+5] = fmaf(wv.z, av.y, acc2[p*8+5]);
        acc2[p*8+6] = fmaf(wv.w, av.x, acc2[p*8+6]);
        acc2[p*8+7] = fmaf(wv.w, av.y, acc2[p*8+7]);
      }
    }
#pragma unroll
    for (int i=0;i<32;i++) mx[i] = fmaxf(mx[i], lrelu(acc2[i]));
  }
  __syncthreads();   // all waves done reading w2T -> reuse as merge buffer
#pragma unroll
  for (int rr=0;rr<2;rr++){
#pragma unroll
    for (int p=0;p<4;p++){
      float4 a = make_float4(mx[p*8+0+rr], mx[p*8+2+rr], mx[p*8+4+rr], mx[p*8+6+rr]);
      *(float4*)&w2T[w*2048 + (r0+rr)*128 + p*32 + oq*4] = a;
    }
  }
  __syncthreads();
  for (int i=tid; i<2048; i+=256){
    float vv = fmaxf(fmaxf(w2T[i], w2T[2048+i]), fmaxf(w2T[4096+i], w2T[6144+i]));
    int r = i>>7, o = i&127;
    tT[((size_t)b*N + n0 + r)*128 + o] = vv;
  }
}

// ---- edgeB: 3ch -> 64 -> 64, max over k ----
__global__ __launch_bounds__(128) void edgeB_kernel(
    const float* __restrict__ xp, const int* __restrict__ idxT,
    const float* __restrict__ w1, const float* __restrict__ w2,
    float* __restrict__ catT, int N){
  __shared__ float w1aT[3*64];
  __shared__ float wd3T[3*64];
  __shared__ float w2T[64*64];
  __shared__ float aT3[2][3*32];
  __shared__ float s1T[2][64*32];
  const int tid = threadIdx.x, w = tid>>6, lane = tid&63;
  const int oq = lane&7, rg = lane>>3;
  const int o0 = oq*8, r0 = rg*4;
  const int b = blockIdx.y, n0 = blockIdx.x*32;
  for (int i=tid; i<192; i+=128){
    int o = i&63, c = i>>6;
    float a = w1[o*6+c], bb = w1[o*6+3+c];
    w1aT[c*64+o] = a; wd3T[c*64+o] = bb - a;
  }
  for (int i=tid; i<64*64; i+=128){
    int o = i>>6, c = i&63;
    w2T[c*64+o] = w2[o*64+c];
  }
  if (tid < 32){
#pragma unroll
    for (int c=0;c<3;c++) aT3[0][c*32+tid] = xp[((size_t)b*3+c)*N + n0 + tid];
  }
  __syncthreads();
  float base[32];
#pragma unroll
  for (int i=0;i<32;i++) base[i]=0.f;
#pragma unroll
  for (int c=0;c<3;c++){
    float4 w0 = ld4(&wd3T[c*64+o0]), w1v = ld4(&wd3T[c*64+o0+4]);
    float4 av = ld4(&aT3[0][c*32+r0]);
    float wv[8] = {w0.x,w0.y,w0.z,w0.w,w1v.x,w1v.y,w1v.z,w1v.w};
    float rv[4] = {av.x,av.y,av.z,av.w};
#pragma unroll
    for (int oo=0;oo<8;oo++)
#pragma unroll
      for (int rr=0;rr<4;rr++) base[oo*4+rr] = fmaf(wv[oo], rv[rr], base[oo*4+rr]);
  }
  __syncthreads();
  float mx[32];
#pragma unroll
  for (int i=0;i<32;i++) mx[i] = -__builtin_inff();
  for (int it=0; it<20; it++){
    int k = it*2 + w;
    {
      int row = lane&31;
      int m = idxT[((size_t)b*KNN + k)*N + n0 + row];
      if (lane < 32){
#pragma unroll
        for (int c=0;c<3;c++) aT3[w][c*32+row] = xp[((size_t)b*3+c)*N + m];
      }
    }
    float acc[32];
#pragma unroll
    for (int i=0;i<32;i++) acc[i] = base[i];
#pragma unroll
    for (int c=0;c<3;c++){
      float4 w0 = ld4(&w1aT[c*64+o0]), w1v = ld4(&w1aT[c*64+o0+4]);
      float4 av = ld4(&aT3[w][c*32+r0]);
      float wv[8] = {w0.x,w0.y,w0.z,w0.w,w1v.x,w1v.y,w1v.z,w1v.w};
      float rv[4] = {av.x,av.y,av.z,av.w};
#pragma unroll
      for (int oo=0;oo<8;oo++)
#pragma unroll
        for (int rr=0;rr<4;rr++) acc[oo*4+rr] = fmaf(wv[oo], rv[rr], acc[oo*4+rr]);
    }
#pragma unroll
    for (int oo=0;oo<8;oo++){
      float4 sv = make_float4(lrelu(acc[oo*4+0]), lrelu(acc[oo*4+1]), lrelu(acc[oo*4+2]), lrelu(acc[oo*4+3]));
      *(float4*)&s1T[w][(o0+oo)*32 + r0] = sv;
    }
    float acc2[32];
#pragma unroll
    for (int i=0;i<32;i++) acc2[i]=0.f;
    for (int c=0;c<64;c++){
      float4 w0 = ld4(&w2T[c*64+o0]), w1v = ld4(&w2T[c*64+o0+4]);
      float4 av = ld4(&s1T[w][c*32+r0]);
      float wv[8] = {w0.x,w0.y,w0.z,w0.w,w1v.x,w1v.y,w1v.z,w1v.w};
      float rv[4] = {av.x,av.y,av.z,av.w};
#pragma unroll
      for (int oo=0;oo<8;oo++)
#pragma unroll
        for (int rr=0;rr<4;rr++) acc2[oo*4+rr] = fmaf(wv[oo], rv[rr], acc2[oo*4+rr]);
    }
#pragma unroll
    for (int i=0;i<32;i++) mx[i] = fmaxf(mx[i], lrelu(acc2[i]));
  }
  __syncthreads();
#pragma unroll
  for (int rr=0;rr<4;rr++){
    float4 a = make_float4(mx[0*4+rr], mx[1*4+rr], mx[2*4+rr], mx[3*4+rr]);
    float4 bq = make_float4(mx[4*4+rr], mx[5*4+rr], mx[6*4+rr], mx[7*4+rr]);
    *(float4*)&s1T[w][(r0+rr)*64 + o0] = a;
    *(float4*)&s1T[w][(r0+rr)*64 + o0 + 4] = bq;
  }
  __syncthreads();
  for (int i=tid; i<2048; i+=128){
    float v = fmaxf(s1T[0][i], s1T[1][i]);
    int r = i>>6, o = i&63;
    catT[((size_t)b*N + n0 + r)*192 + o] = v;
  }
}

// ---- edgeC: 64ch -> 64 -> 64, max over k ----
__global__ __launch_bounds__(128) void edgeC_kernel(
    const float* __restrict__ inT, int inOff, const int* __restrict__ idxT,
    const float* __restrict__ w1, const float* __restrict__ w2,
    float* __restrict__ catT, int outOff, int N){
  __shared__ float w1T[64*64];
  __shared__ float w2T[64*64];
  __shared__ float aT[2][64*32];
  __shared__ float s1T[2][64*32];
  const int tid = threadIdx.x, w = tid>>6, lane = tid&63;
  const int oq = lane&7, rg = lane>>3;
  const int o0 = oq*8, r0 = rg*4;
  const int b = blockIdx.y, n0 = blockIdx.x*32;
  for (int i=tid; i<64*64; i+=128){
    int o = i>>6, c = i&63;
    float a = w1[o*128+c], bb = w1[o*128+64+c];
    w1T[c*64+o] = a; w2T[c*64+o] = bb - a;
  }
  for (int i=tid; i<512; i+=128){
    int p = i>>4, cq = i&15;
    float4 v = ld4(&inT[((size_t)b*N + n0 + p)*192 + inOff + cq*4]);
    aT[0][(cq*4+0)*32+p] = v.x; aT[0][(cq*4+1)*32+p] = v.y;
    aT[0][(cq*4+2)*32+p] = v.z; aT[0][(cq*4+3)*32+p] = v.w;
  }
  __syncthreads();
  float base[32];
#pragma unroll
  for (int i=0;i<32;i++) base[i]=0.f;
  for (int c=0;c<64;c++){
    float4 w0 = ld4(&w2T[c*64+o0]), w1v = ld4(&w2T[c*64+o0+4]);
    float4 av = ld4(&aT[0][c*32+r0]);
    float wv[8] = {w0.x,w0.y,w0.z,w0.w,w1v.x,w1v.y,w1v.z,w1v.w};
    float rv[4] = {av.x,av.y,av.z,av.w};
#pragma unroll
    for (int oo=0;oo<8;oo++)
#pragma unroll
      for (int rr=0;rr<4;rr++) base[oo*4+rr] = fmaf(wv[oo], rv[rr], base[oo*4+rr]);
  }
  __syncthreads();
  for (int i=tid; i<64*64; i+=128){
    int o = i>>6, c = i&63;
    w2T[c*64+o] = w2[o*64+c];
  }
  __syncthreads();
  float mx[32];
#pragma unroll
  for (int i=0;i<32;i++) mx[i] = -__builtin_inff();
  const int row = lane&31, ch = lane>>5;
  for (int it=0; it<20; it++){
    int k = it*2 + w;
    {
      int m = idxT[((size_t)b*KNN + k)*N + n0 + row];
      const float* src = &inT[((size_t)b*N + m)*192 + inOff + ch*32];
      float4 g[8];
#pragma unroll
      for (int j=0;j<8;j++) g[j] = ld4(src + j*4);
#pragma unroll
      for (int j=0;j<8;j++){
        aT[w][(ch*32+j*4+0)*32 + row] = g[j].x;
        aT[w][(ch*32+j*4+1)*32 + row] = g[j].y;
        aT[w][(ch*32+j*4+2)*32 + row] = g[j].z;
        aT[w][(ch*32+j*4+3)*32 + row] = g[j].w;
      }
    }
    float acc[32];
#pragma unroll
    for (int i=0;i<32;i++) acc[i] = base[i];
    for (int c=0;c<64;c++){
      float4 w0 = ld4(&w1T[c*64+o0]), w1v = ld4(&w1T[c*64+o0+4]);
      float4 av = ld4(&aT[w][c*32+r0]);
      float wv[8] = {w0.x,w0.y,w0.z,w0.w,w1v.x,w1v.y,w1v.z,w1v.w};
      float rv[4] = {av.x,av.y,av.z,av.w};
#pragma unroll
      for (int oo=0;oo<8;oo++)
#pragma unroll
        for (int rr=0;rr<4;rr++) acc[oo*4+rr] = fmaf(wv[oo], rv[rr], acc[oo*4+rr]);
    }
#pragma unroll
    for (int oo=0;oo<8;oo++){
      float4 sv = make_float4(lrelu(acc[oo*4+0]), lrelu(acc[oo*4+1]), lrelu(acc[oo*4+2]), lrelu(acc[oo*4+3]));
      *(float4*)&s1T[w][(o0+oo)*32 + r0] = sv;
    }
    float acc2[32];
#pragma unroll
    for (int i=0;i<32;i++) acc2[i]=0.f;
    for (int c=0;c<64;c++){
      float4 w0 = ld4(&w2T[c*64+o0]), w1v = ld4(&w2T[c*64+o0+4]);
      float4 av = ld4(&s1T[w][c*32+r0]);
      float wv[8] = {w0.x,w0.y,w0.z,w0.w,w1v.x,w1v.y,w1v.z,w1v.w};
      float rv[4] = {av.x,av.y,av.z,av.w};
#pragma unroll
      for (int oo=0;oo<8;oo++)
#pragma unroll
        for (int rr=0;rr<4;rr++) acc2[oo*4+rr] = fmaf(wv[oo], rv[rr], acc2[oo*4+rr]);
    }
#pragma unroll
    for (int i=0;i<32;i++) mx[i] = fmaxf(mx[i], lrelu(acc2[i]));
  }
  __syncthreads();
#pragma unroll
  for (int rr=0;rr<4;rr++){
    float4 a = make_float4(mx[0*4+rr], mx[1*4+rr], mx[2*4+rr], mx[3*4+rr]);
    float4 bq = make_float4(mx[4*4+rr], mx[5*4+rr], mx[6*4+rr], mx[7*4+rr]);
    *(float4*)&s1T[w][(r0+rr)*64 + o0] = a;
    *(float4*)&s1T[w][(r0+rr)*64 + o0 + 4] = bq;
  }
  __syncthreads();
  for (int i=tid; i<2048; i+=128){
    float v = fmaxf(s1T[0][i], s1T[1][i]);
    int r = i>>6, o = i&63;
    catT[((size_t)b*N + n0 + r)*192 + outOff + o] = v;
  }
}

// ---- edgeD: 64ch -> 64 (single conv), max over k ----
__global__ __launch_bounds__(128) void edgeD_kernel(
    const float* __restrict__ inT, int inOff, const int* __restrict__ idxT,
    const float* __restrict__ w1, float* __restrict__ catT, int outOff, int N){
  __shared__ float w1T[64*64];
  __shared__ float wdT[64*64];
  __shared__ float aT[2][64*32];
  const int tid = threadIdx.x, w = tid>>6, lane = tid&63;
  const int oq = lane&7, rg = lane>>3;
  const int o0 = oq*8, r0 = rg*4;
  const int b = blockIdx.y, n0 = blockIdx.x*32;
  for (int i=tid; i<64*64; i+=128){
    int o = i>>6, c = i&63;
    float a = w1[o*128+c], bb = w1[o*128+64+c];
    w1T[c*64+o] = a; wdT[c*64+o] = bb - a;
  }
  for (int i=tid; i<512; i+=128){
    int p = i>>4, cq = i&15;
    float4 v = ld4(&inT[((size_t)b*N + n0 + p)*192 + inOff + cq*4]);
    aT[0][(cq*4+0)*32+p] = v.x; aT[0][(cq*4+1)*32+p] = v.y;
    aT[0][(cq*4+2)*32+p] = v.z; aT[0][(cq*4+3)*32+p] = v.w;
  }
  __syncthreads();
  float base[32];
#pragma unroll
  for (int i=0;i<32;i++) base[i]=0.f;
  for (int c=0;c<64;c++){
    float4 w0 = ld4(&wdT[c*64+o0]), w1v = ld4(&wdT[c*64+o0+4]);
    float4 av = ld4(&aT[0][c*32+r0]);
    float wv[8] = {w0.x,w0.y,w0.z,w0.w,w1v.x,w1v.y,w1v.z,w1v.w};
    float rv[4] = {av.x,av.y,av.z,av.w};
#pragma unroll
    for (int oo=0;oo<8;oo++)
#pragma unroll
      for (int rr=0;rr<4;rr++) base[oo*4+rr] = fmaf(wv[oo], rv[rr], base[oo*4+rr]);
  }
  __syncthreads();
  float mx[32];
#pragma unroll
  for (int i=0;i<32;i++) mx[i] = -__builtin_inff();
  const int row = lane&31, ch = lane>>5;
  for (int it=0; it<20; it++){
    int k = it*2 + w;
    {
      int m = idxT[((size_t)b*KNN + k)*N + n0 + row];
      const float* src = &inT[((size_t)b*N + m)*192 + inOff + ch*32];
      float4 g[8];
#pragma unroll
      for (int j=0;j<8;j++) g[j] = ld4(src + j*4);
#pragma unroll
      for (int j=0;j<8;j++){
        aT[w][(ch*32+j*4+0)*32 + row] = g[j].x;
        aT[w][(ch*32+j*4+1)*32 + row] = g[j].y;
        aT[w][(ch*32+j*4+2)*32 + row] = g[j].z;
        aT[w][(ch*32+j*4+3)*32 + row] = g[j].w;
      }
    }
    float acc[32];
#pragma unroll
    for (int i=0;i<32;i++) acc[i] = base[i];
    for (int c=0;c<64;c++){
      float4 w0 = ld4(&w1T[c*64+o0]), w1v = ld4(&w1T[c*64+o0+4]);
      float4 av = ld4(&aT[w][c*32+r0]);
      float wv[8] = {w0.x,w0.y,w0.z,w0.w,w1v.x,w1v.y,w1v.z,w1v.w};
      float rv[4] = {av.x,av.y,av.z,av.w};
#pragma unroll
      for (int oo=0;oo<8;oo++)
#pragma unroll
        for (int rr=0;rr<4;rr++) acc[oo*4+rr] = fmaf(wv[oo], rv[rr], acc[oo*4+rr]);
    }
#pragma unroll
    for (int i=0;i<32;i++) mx[i] = fmaxf(mx[i], lrelu(acc[i]));
  }
  __syncthreads();
#pragma unroll
  for (int rr=0;rr<4;rr++){
    float4 a = make_float4(mx[0*4+rr], mx[1*4+rr], mx[2*4+rr], mx[3*4+rr]);
    float4 bq = make_float4(mx[4*4+rr], mx[5*4+rr], mx[6*4+rr], mx[7*4+rr]);
    *(float4*)&wdT[w*2048 + (r0+rr)*64 + o0] = a;
    *(float4*)&wdT[w*2048 + (r0+rr)*64 + o0 + 4] = bq;
  }
  __syncthreads();
  for (int i=tid; i<2048; i+=128){
    float v = fmaxf(wdT[i], wdT[2048+i]);
    int r = i>>6, o = i&63;
    catT[((size_t)b*N + n0 + r)*192 + outOff + o] = v;
  }
}

// ---------------- conv1 (1024 outs) + lrelu + max -- register-tiled, weights in LDS ----------------
template<int CIN, int TAG>
__global__ __launch_bounds__(128) void convmax_kernel(
    const float* __restrict__ inT, const float* __restrict__ wT,
    float* __restrict__ partial, int N){
  __shared__ float wsh[CIN*64];
  __shared__ float ish[32*CIN];     // [c][32]
  const int tid = threadIdx.x, w = tid>>6, lane = tid&63;
  const int oq = lane&7, rg = lane>>3;
  const int o0 = oq*8, r0 = rg*4;
  const int b = blockIdx.z, oc = blockIdx.x, nt = blockIdx.y;
  for (int i=tid; i<CIN*64; i+=128){
    int c = i>>6, o = i&63;
    wsh[i] = wT[(size_t)c*1024 + oc*64 + o];
  }
  float mx[32];
#pragma unroll
  for (int i=0;i<32;i++) mx[i] = -__builtin_inff();
  const int nbase = nt*(N/8);
  for (int st=0; st<8; st++){
    __syncthreads();
    const float* src = inT + ((size_t)b*N + nbase + st*32)*CIN;
    for (int i=tid; i<32*(CIN/4); i+=128){
      int p = i/(CIN/4), cq = i%(CIN/4);
      float4 v = ld4(src + p*CIN + 4*cq);
      ish[(4*cq+0)*32+p]=v.x; ish[(4*cq+1)*32+p]=v.y;
      ish[(4*cq+2)*32+p]=v.z; ish[(4*cq+3)*32+p]=v.w;
    }
    __syncthreads();
    float acc[32];
#pragma unroll
    for (int i=0;i<32;i++) acc[i]=0.f;
    for (int c=0;c<CIN;c++){
      float4 w0 = ld4(&wsh[c*64+o0]), w1v = ld4(&wsh[c*64+o0+4]);
      float4 av = ld4(&ish[c*32+r0]);
      float wv[8] = {w0.x,w0.y,w0.z,w0.w,w1v.x,w1v.y,w1v.z,w1v.w};
      float rv[4] = {av.x,av.y,av.z,av.w};
#pragma unroll
      for (int oo=0;oo<8;oo++)
#pragma unroll
        for (int rr=0;rr<4;rr++) acc[oo*4+rr] = fmaf(wv[oo], rv[rr], acc[oo*4+rr]);
    }
#pragma unroll
    for (int i=0;i<32;i++) mx[i] = fmaxf(mx[i], lrelu(acc[i]));
  }
  float m8[8];
#pragma unroll
  for (int oo=0;oo<8;oo++)
    m8[oo] = fmaxf(fmaxf(mx[oo*4+0], mx[oo*4+1]), fmaxf(mx[oo*4+2], mx[oo*4+3]));
  __syncthreads();
  *(float4*)&ish[(w*8+rg)*64 + o0]     = make_float4(m8[0],m8[1],m8[2],m8[3]);
  *(float4*)&ish[(w*8+rg)*64 + o0 + 4] = make_float4(m8[4],m8[5],m8[6],m8[7]);
  __syncthreads();
  if (tid < 64){
    float v = -__builtin_inff();
#pragma unroll
    for (int g=0; g<16; g++) v = fmaxf(v, ish[g*64+tid]);
    partial[((size_t)b*8 + nt)*1024 + oc*64 + tid] = v;
  }
}

template<int TAG>
__global__ void reduce_max_kernel(const float* __restrict__ partial, float* __restrict__ out){
  int b = blockIdx.y; int o = blockIdx.x*256 + threadIdx.x;
  float v = -__builtin_inff();
  for (int s=0;s<8;s++) v = fmaxf(v, partial[((size_t)b*8 + s)*1024 + o]);
  out[(size_t)b*1024 + o] = v;
}

// ---------------- small FC ----------------
__global__ void fc_kernel(const float* __restrict__ in, const float* __restrict__ W,
                          const float* __restrict__ bias, float* __restrict__ out,
                          int CI, int O, int act){
  int b = blockIdx.x;
  __shared__ float insh[1024];
  for (int i=threadIdx.x;i<CI;i+=blockDim.x) insh[i]=in[(size_t)b*CI+i];
  __syncthreads();
  for (int o=threadIdx.x;o<O;o+=blockDim.x){
    float s = bias ? bias[o] : 0.f;
    for (int c=0;c<CI;c++) s = fmaf(W[(size_t)o*CI+c], insh[c], s);
    if (act) s = lrelu(s);
    out[(size_t)b*O+o]=s;
  }
}

// ---------------- x' = T^T x per batch ----------------
__global__ void transform_kernel(const float* __restrict__ x, const float* __restrict__ T9,
                                 float* __restrict__ xp, int N){
  int b = blockIdx.y; int n = blockIdx.x*256 + threadIdx.x;
  const float* t = T9 + (size_t)b*9;
  float x0=x[((size_t)b*3+0)*N+n], x1=x[((size_t)b*3+1)*N+n], x2=x[((size_t)b*3+2)*N+n];
#pragma unroll
  for (int i=0;i<3;i++)
    xp[((size_t)b*3+i)*N+n] = t[i]*x0 + t[3+i]*x1 + t[6+i]*x2;
}

// ---------------- bias1: n-invariant part of h1 ----------------
__global__ void bias1_kernel(const float* __restrict__ g, const float* __restrict__ lv,
                             const float* __restrict__ h1w, float* __restrict__ bias1){
  int b = blockIdx.x;
  __shared__ float insh[1088];
  for (int i=threadIdx.x;i<1088;i+=256) insh[i] = (i<1024)? g[(size_t)b*1024+i] : lv[(size_t)b*64 + (i-1024)];
  __syncthreads();
  int o = threadIdx.x;
  float s=0.f;
  for (int c=0;c<1088;c++) s = fmaf(h1w[(size_t)o*1280+c], insh[c], s);
  bias1[(size_t)b*256+o]=s;
}

// ---------------- head conv layers ----------------
template<int CI, int O, bool ACT>
__global__ __launch_bounds__(256) void conv1_kernel(
    const float* __restrict__ inT, const float* __restrict__ wT,
    const float* __restrict__ bias, float* __restrict__ outT, int N){
  const int b = blockIdx.y, n0 = blockIdx.x*32;
  __shared__ float insh[32*CI];
  const float* src = inT + ((size_t)b*N + n0)*CI;
  for (int i=threadIdx.x;i<32*CI;i+=256) insh[i] = src[i];
  __syncthreads();
  constexpr int NREP = 256/O;
  constexpr int NLOC = 32/NREP;
  const int o = threadIdx.x % O, rep = threadIdx.x / O;
  float acc[NLOC];
#pragma unroll
  for (int t=0;t<NLOC;t++) acc[t]=0.f;
  for (int c=0;c<CI;c++){
    float wv = wT[c*O + o];
#pragma unroll
    for (int t=0;t<NLOC;t++) acc[t] = fmaf(wv, insh[(t*NREP+rep)*CI + c], acc[t]);
  }
  float bv = bias ? bias[(size_t)b*O + o] : 0.f;
#pragma unroll
  for (int t=0;t<NLOC;t++){
    float s = acc[t] + bv;
    if (ACT) s = lrelu(s);
    outT[((size_t)b*N + n0 + t*NREP + rep)*O + o] = s;
  }
}

// ---------------- final layer: 128 -> 50, rows-layout output (B,50,N) ----------------
__global__ __launch_bounds__(256) void conv_out_kernel(
    const float* __restrict__ inT, const float* __restrict__ wT,
    float* __restrict__ out, int N){
  const int b = blockIdx.y, n0 = blockIdx.x*32;
  __shared__ float insh[32*129];
  const float* src = inT + ((size_t)b*N + n0)*128;
  for (int i=threadIdx.x;i<32*128;i+=256){ int nn=i>>7, c=i&127; insh[nn*129+c]=src[i]; }
  __syncthreads();
  const int nl = threadIdx.x & 31, og = threadIdx.x >> 5;
  float acc[7];
#pragma unroll
  for (int t=0;t<7;t++) acc[t]=0.f;
  for (int c=0;c<128;c++){
    float iv = insh[nl*129+c];
#pragma unroll
    for (int t=0;t<7;t++){
      int o = og + 8*t;
      float wv = (o<50)? wT[c*50+o] : 0.f;
      acc[t] = fmaf(wv, iv, acc[t]);
    }
  }
#pragma unroll
  for (int t=0;t<7;t++){
    int o = og + 8*t;
    if (o < 50) out[((size_t)b*50+o)*N + n0 + nl] = acc[t];
  }
}

extern "C" void kernel_launch(void* const* d_in, const int* in_sizes, int n_in,
                              void* d_out, int out_size, void* d_ws, size_t ws_size,
                              hipStream_t stream){
  const float* x    = (const float*)d_in[0];
  const float* l    = (const float*)d_in[1];
  const float* t_c1 = (const float*)d_in[2];
  const float* t_c2 = (const float*)d_in[3];
  const float* t_c3 = (const float*)d_in[4];
  const float* t_f1 = (const float*)d_in[5];
  const float* t_f2 = (const float*)d_in[6];
  const float* t_f3w= (const float*)d_in[7];
  const float* t_f3b= (const float*)d_in[8];
  const float* b1a  = (const float*)d_in[9];
  const float* b1b  = (const float*)d_in[10];
  const float* b2a  = (const float*)d_in[11];
  const float* b2b  = (const float*)d_in[12];
  const float* b3a  = (const float*)d_in[13];
  const float* m1   = (const float*)d_in[14];
  const float* m2   = (const float*)d_in[15];
  const float* h1   = (const float*)d_in[16];
  const float* h2   = (const float*)d_in[17];
  const float* h3   = (const float*)d_in[18];
  const float* h4   = (const float*)d_in[19];
  float* out = (float*)d_out;
  float* ws = (float*)d_ws;
  const int N = NPTS, B = BATCH;

  size_t off = 0;
  auto alloc = [&](size_t nf){ float* p = ws + off; off += nf; return p; };
  float* WT_TC3 = alloc((size_t)128*1024);
  float* WT_M1  = alloc((size_t)192*1024);
  float* WT_H1B = alloc((size_t)192*256);
  float* WT_H2  = alloc((size_t)256*256);
  float* WT_H3  = alloc((size_t)256*128);
  float* WT_H4  = alloc((size_t)128*64);
  int*   IDXT   = (int*)alloc((size_t)B*N*KNN);
  float* XX     = alloc((size_t)B*N);
  float* TT     = alloc((size_t)B*N*128);
  float* PARTIAL= alloc((size_t)B*8*1024);
  float* TG     = alloc((size_t)B*1024);
  float* T512   = alloc((size_t)B*512);
  float* T256   = alloc((size_t)B*256);
  float* T9     = alloc((size_t)B*16);
  float* XP     = alloc((size_t)B*3*N);
  float* CATT   = alloc((size_t)B*N*192);
  float* G      = alloc((size_t)B*1024);
  float* LV     = alloc((size_t)B*64);
  float* BIAS1  = alloc((size_t)B*256);
  float* H1T    = alloc((size_t)B*N*256);
  float* H2T    = alloc((size_t)B*N*256);
  float* H3T    = alloc((size_t)B*N*128);
  (void)ws_size; (void)in_sizes; (void)n_in; (void)out_size;

  dim3 blk(256);
  dim3 eblk(128);
  // weight transposes
  transpose_kernel<<<dim3((1024*128+255)/256), blk, 0, stream>>>(t_c3, WT_TC3, 1024,128,128,0);
  transpose_kernel<<<dim3((1024*192+255)/256), blk, 0, stream>>>(m1,  WT_M1, 1024,192,192,0);
  transpose_kernel<<<dim3((256*192+255)/256),  blk, 0, stream>>>(h1, WT_H1B, 256,192,1280,1088);
  transpose_kernel<<<dim3((256*256+255)/256),  blk, 0, stream>>>(h2, WT_H2, 256,256,256,0);
  transpose_kernel<<<dim3((128*256+255)/256),  blk, 0, stream>>>(h3, WT_H3, 128,256,256,0);
  transpose_kernel<<<dim3((50*128+255)/256),   blk, 0, stream>>>(h4, WT_H4, 50,128,128,0);

  // t-path
  norms_rows_kernel<0><<<dim3(N/256,B), blk, 0, stream>>>(x, XX, N);
  knn3_kernel<0><<<dim3(N/4,B), blk, 0, stream>>>(x, XX, IDXT, N);
  edgeA_kernel<<<dim3(N/16,B), blk, 0, stream>>>(x, IDXT, t_c1, t_c2, TT, N);
  convmax_kernel<128,0><<<dim3(16,8,B), eblk, 0, stream>>>(TT, WT_TC3, PARTIAL, N);
  reduce_max_kernel<0><<<dim3(4,B), blk, 0, stream>>>(PARTIAL, TG);
  fc_kernel<<<dim3(B), dim3(512), 0, stream>>>(TG, t_f1, nullptr, T512, 1024, 512, 1);
  fc_kernel<<<dim3(B), dim3(512), 0, stream>>>(T512, t_f2, nullptr, T256, 512, 256, 1);
  fc_kernel<<<dim3(B), dim3(512), 0, stream>>>(T256, t_f3w, t_f3b, T9, 256, 9, 0);
  transform_kernel<<<dim3(N/256,B), blk, 0, stream>>>(x, T9, XP, N);

  // edge block 1 (transformed points, 3ch)
  norms_rows_kernel<1><<<dim3(N/256,B), blk, 0, stream>>>(XP, XX, N);
  knn3_kernel<1><<<dim3(N/4,B), blk, 0, stream>>>(XP, XX, IDXT, N);
  edgeB_kernel<<<dim3(N/32,B), eblk, 0, stream>>>(XP, IDXT, b1a, b1b, CATT, N);

  // edge block 2 (x1 = CATT[...,0:64])
  norms_cl_kernel<0><<<dim3(N/256,B), blk, 0, stream>>>(CATT, 0, XX, N);
  knn64_kernel<0><<<dim3(N/4,B), blk, 0, stream>>>(CATT, 0, XX, IDXT, N);
  edgeC_kernel<<<dim3(N/32,B), eblk, 0, stream>>>(CATT, 0, IDXT, b2a, b2b, CATT, 64, N);

  // edge block 3 (x2 = CATT[...,64:128])
  norms_cl_kernel<1><<<dim3(N/256,B), blk, 0, stream>>>(CATT, 64, XX, N);
  knn64_kernel<1><<<dim3(N/4,B), blk, 0, stream>>>(CATT, 64, XX, IDXT, N);
  edgeD_kernel<<<dim3(N/32,B), eblk, 0, stream>>>(CATT, 64, IDXT, b3a, CATT, 128, N);

  // global feature + head
  convmax_kernel<192,1><<<dim3(16,8,B), eblk, 0, stream>>>(CATT, WT_M1, PARTIAL, N);
  reduce_max_kernel<1><<<dim3(4,B), blk, 0, stream>>>(PARTIAL, G);
  fc_kernel<<<dim3(B), dim3(512), 0, stream>>>(l, m2, nullptr, LV, 16, 64, 1);
  bias1_kernel<<<dim3(B), blk, 0, stream>>>(G, LV, h1, BIAS1);
  conv1_kernel<192,256,true><<<dim3(N/32,B), blk, 0, stream>>>(CATT, WT_H1B, BIAS1, H1T, N);
  conv1_kernel<256,256,true><<<dim3(N/32,B), blk, 0, stream>>>(H1T, WT_H2, nullptr, H2T, N);
  conv1_kernel<256,128,true><<<dim3(N/32,B), blk, 0, stream>>>(H2T, WT_H3, nullptr, H3T, N);
  conv_out_kernel<<<dim3(N/32,B), blk, 0, stream>>>(H3T, WT_H4, out, N);
}

// Round 12
// 2371.241 us; speedup vs baseline: 1.0973x; 1.0973x over previous
//
#include <hip/hip_runtime.h>
#include <cstdint>

#define NPTS 2048
#define BATCH 8
#define KNN 40

__device__ __forceinline__ float lrelu(float v){ return fmaxf(v, 0.2f*v); }
__device__ __forceinline__ bool better(float v1,int i1,float v2,int i2){
  return (v1>v2) || (v1==v2 && i1<i2);
}
__device__ __forceinline__ float4 ld4(const float* p){ return *(const float4*)p; }

// insert (d,m) into sorted-desc 8-list if it beats the tail; static CE chain.
#define INSERT8(v,id,d,m) \
  if (better(d, m, v[7], id[7])){ \
    v[7]=d; id[7]=m; \
    { if (better(v[7],id[7],v[6],id[6])){ float tv=v[6];int ti=id[6]; v[6]=v[7];id[6]=id[7]; v[7]=tv;id[7]=ti; } } \
    { if (better(v[6],id[6],v[5],id[5])){ float tv=v[5];int ti=id[5]; v[5]=v[6];id[5]=id[6]; v[6]=tv;id[6]=ti; } } \
    { if (better(v[5],id[5],v[4],id[4])){ float tv=v[4];int ti=id[4]; v[4]=v[5];id[4]=id[5]; v[5]=tv;id[5]=ti; } } \
    { if (better(v[4],id[4],v[3],id[3])){ float tv=v[3];int ti=id[3]; v[3]=v[4];id[3]=id[4]; v[4]=tv;id[4]=ti; } } \
    { if (better(v[3],id[3],v[2],id[2])){ float tv=v[2];int ti=id[2]; v[2]=v[3];id[2]=id[3]; v[3]=tv;id[3]=ti; } } \
    { if (better(v[2],id[2],v[1],id[1])){ float tv=v[1];int ti=id[1]; v[1]=v[2];id[1]=id[2]; v[2]=tv;id[2]=ti; } } \
    { if (better(v[1],id[1],v[0],id[0])){ float tv=v[0];int ti=id[0]; v[0]=v[1];id[0]=id[1]; v[1]=tv;id[1]=ti; } } \
  }

// ---------------- generic transpose: dst[c*R+r] = src[r*ld+off+c] ----------------
__global__ void transpose_kernel(const float* __restrict__ src, float* __restrict__ dst,
                                 int R, int C, int ld, int off){
  int i = blockIdx.x*256 + threadIdx.x;
  if (i < R*C){ int r = i / C, c = i % C; dst[c*R + r] = src[r*ld + off + c]; }
}

// ---------------- squared norms, rows layout (B,3,N) ----------------
template<int TAG>
__global__ void norms_rows_kernel(const float* __restrict__ x, float* __restrict__ xx, int N){
  int b = blockIdx.y; int n = blockIdx.x*256 + threadIdx.x;
  const float* xb = x + (size_t)b*3*N;
  float v0 = xb[n], v1 = xb[N+n], v2 = xb[2*N+n];
  xx[(size_t)b*N + n] = v0*v0 + v1*v1 + v2*v2;
}

// ---------------- squared norms, channel-last 64ch slice of (B,N,192) ----------------
template<int TAG>
__global__ void norms_cl_kernel(const float* __restrict__ f, int off, float* __restrict__ xx, int N){
  int b = blockIdx.y; int n = blockIdx.x*256 + threadIdx.x;
  const float4* p = (const float4*)(f + ((size_t)b*N + n)*192 + off);
  float s = 0.f;
#pragma unroll
  for (int q=0;q<16;q++){ float4 v = p[q]; s += v.x*v.x + v.y*v.y + v.z*v.z + v.w*v.w; }
  xx[(size_t)b*N + n] = s;
}

__device__ __forceinline__ void sort8(float (&v)[8], int (&id)[8]){
#define CE(a,bq) { if (better(v[bq],id[bq],v[a],id[a])){ float tv=v[a]; int ti=id[a]; v[a]=v[bq]; id[a]=id[bq]; v[bq]=tv; id[bq]=ti; } }
  CE(0,1) CE(2,3) CE(4,5) CE(6,7)
  CE(0,2) CE(1,3) CE(4,6) CE(5,7)
  CE(1,2) CE(5,6)
  CE(0,4) CE(1,5) CE(2,6) CE(3,7)
  CE(2,4) CE(3,5)
  CE(1,2) CE(3,4) CE(5,6)
#undef CE
}

// ---------------- knn 3-channel: 4 queries/block (1/wave), zero LDS, zero barriers ----------------
// Insertion top-8 during dist; 40-round butterfly extraction; rare refill recomputes.
template<int TAG>
__global__ __launch_bounds__(256) void knn3_kernel(
    const float* __restrict__ xrows, const float* __restrict__ xx,
    int* __restrict__ idxT, int N){
  const int b = blockIdx.y, tid = threadIdx.x;
  const int w = tid>>6, lane = tid&63;
  const int nq = blockIdx.x*4 + w;
  const float* xb = xrows + (size_t)b*3*N;
  const float* xxb = xx + (size_t)b*N;
  float c0 = xb[nq], c1 = xb[N+nq], c2 = xb[2*N+nq];
  float xxn = xxb[nq];
  float v[8]; int id[8];
#pragma unroll
  for (int j=0;j<8;j++){ v[j]=-__builtin_inff(); id[j]=0x7FFFFFFF; }
  for (int j=0;j<32;j++){
    int m = j*64 + lane;
    float s = c0*xb[m] + c1*xb[N+m] + c2*xb[2*N+m];
    float d = 2.f*s - xxn - xxb[m];
    INSERT8(v, id, d, m)
  }
  float lastv = 0.f; int lasti = 0;
  int win = 0;
  for (int r=0;r<KNN;r++){
    float bv = v[0]; int bi = id[0];
#pragma unroll
    for (int off=32; off; off>>=1){
      float ov = __shfl_xor(bv, off);
      int   oi = __shfl_xor(bi, off);
      if (better(ov, oi, bv, bi)){ bv = ov; bi = oi; }
    }
    if (lane == r) win = bi;
    if (id[0] == bi){
      lastv = v[0]; lasti = id[0];
#pragma unroll
      for (int j=0;j<7;j++){ v[j]=v[j+1]; id[j]=id[j+1]; }
      v[7] = -__builtin_inff(); id[7] = 0x7FFFFFFF;
      if (id[0] == 0x7FFFFFFF){   // rare refill: best strictly worse than last pop
        float nv = -__builtin_inff(); int ni = 0x7FFFFFFF;
        for (int j=0;j<32;j++){
          int m = j*64 + lane;
          float s = c0*xb[m] + c1*xb[N+m] + c2*xb[2*N+m];
          float dd = 2.f*s - xxn - xxb[m];
          if (better(lastv, lasti, dd, m) && better(dd, m, nv, ni)){ nv=dd; ni=m; }
        }
        v[0] = nv; id[0] = ni;
      }
    }
  }
  if (lane < KNN) idxT[((size_t)b*KNN + lane)*N + nq] = win;
}

// ---------------- knn 64-channel (channel-last), 4 queries/block ----------------
// R10 champion: dist strips in LDS (wave-private), tile prefetch, per-lane sorted
// top-8 built post-hoc (4x sort8 + bitonic top-8 merges), pop extraction, rare refill.
template<int TAG>
__global__ __launch_bounds__(256) void knn64_kernel(
    const float* __restrict__ featT, int featOff,
    const float* __restrict__ xx, int* __restrict__ idxT, int N){
  const int b = blockIdx.y, tid = threadIdx.x;
  const int w = tid>>6, lane = tid&63;
  __shared__ float cand[64*64];    // xor-swizzled [cand][ch] tile, block-shared
  __shared__ float dist[4*2048];   // wave-private strips
  const float* fb = featT + featOff;
  const float* xxb = xx + (size_t)b*N;
  const int nq = blockIdx.x*4 + w;
  float4 ctr[16];
  {
    const float4* cp = (const float4*)(fb + ((size_t)b*N + nq)*192);
#pragma unroll
    for (int q=0;q<16;q++) ctr[q] = cp[q];
  }
  float xxn = xxb[nq];
  float* dw = &dist[w*2048];
  float4 g[4];
#pragma unroll
  for (int r=0;r<4;r++){
    int k2 = tid + 256*r;
    int c = k2>>4, f = k2&15;
    g[r] = ld4(&fb[((size_t)b*N + c)*192 + 4*f]);
  }
  for (int t=0;t<32;t++){
    __syncthreads();                 // prev compute done reading cand
#pragma unroll
    for (int r=0;r<4;r++){
      int k2 = tid + 256*r;
      int c = k2>>4, f = k2&15;
      *(float4*)&cand[(c<<6) + ((f ^ (c&15))<<2)] = g[r];
    }
    __syncthreads();
    if (t+1 < 32){                   // issue next tile's loads; latency overlaps compute
      int m0n = (t+1)*64;
#pragma unroll
      for (int r=0;r<4;r++){
        int k2 = tid + 256*r;
        int c = k2>>4, f = k2&15;
        g[r] = ld4(&fb[((size_t)b*N + m0n + c)*192 + 4*f]);
      }
    }
    float s0=0.f,s1=0.f,s2=0.f,s3=0.f;
#pragma unroll
    for (int u=0;u<16;u++){
      float4 mv = *(const float4*)&cand[(lane<<6) + ((u ^ (lane&15))<<2)];
      s0 = fmaf(ctr[u].x, mv.x, s0);
      s1 = fmaf(ctr[u].y, mv.y, s1);
      s2 = fmaf(ctr[u].z, mv.z, s2);
      s3 = fmaf(ctr[u].w, mv.w, s3);
    }
    dw[t*64 + lane] = 2.f*((s0+s1)+(s2+s3)) - xxn - xxb[t*64 + lane];
  }
  // ---- per-lane exact top-8 of its 32 entries (sorted desc by (v desc, idx asc)) ----
  float v[8]; int id[8];
#pragma unroll
  for (int j=0;j<8;j++){ v[j]=dw[j*64+lane]; id[j]=j*64+lane; }
  sort8(v, id);
#pragma unroll
  for (int gq=1; gq<4; gq++){
    float a[8]; int ai[8];
#pragma unroll
    for (int j=0;j<8;j++){ a[j]=dw[(gq*8+j)*64+lane]; ai[j]=(gq*8+j)*64+lane; }
    sort8(a, ai);
    float m_[8]; int mi_[8];
#pragma unroll
    for (int k=0;k<8;k++){
      if (better(a[7-k], ai[7-k], v[k], id[k])){ m_[k]=a[7-k]; mi_[k]=ai[7-k]; }
      else                                     { m_[k]=v[k];   mi_[k]=id[k]; }
    }
#define CEB(x,y) { if (better(m_[y],mi_[y],m_[x],mi_[x])){ float tv=m_[x];int ti=mi_[x]; m_[x]=m_[y];mi_[x]=mi_[y]; m_[y]=tv;mi_[y]=ti; } }
    CEB(0,4) CEB(1,5) CEB(2,6) CEB(3,7)
    CEB(0,2) CEB(1,3) CEB(4,6) CEB(5,7)
    CEB(0,1) CEB(2,3) CEB(4,5) CEB(6,7)
#undef CEB
#pragma unroll
    for (int k=0;k<8;k++){ v[k]=m_[k]; id[k]=mi_[k]; }
  }
  // ---- 40 extraction rounds: butterfly + pop-shift; zero barriers, zero LDS steady state ----
  float lastv = 0.f; int lasti = 0;
  int win = 0;
  for (int r=0;r<KNN;r++){
    float bv = v[0]; int bi = id[0];
#pragma unroll
    for (int off=32; off; off>>=1){
      float ov = __shfl_xor(bv, off);
      int   oi = __shfl_xor(bi, off);
      if (better(ov, oi, bv, bi)){ bv = ov; bi = oi; }
    }
    if (lane == r) win = bi;
    if (id[0] == bi){                // unique owner (indices unique)
      lastv = v[0]; lasti = id[0];
#pragma unroll
      for (int j=0;j<7;j++){ v[j]=v[j+1]; id[j]=id[j+1]; }
      v[7] = -__builtin_inff(); id[7] = 0x7FFFFFFF;
      if (id[0] == 0x7FFFFFFF){      // rare: lane contributed >8 of top-40 -> refill head
        float nv = -__builtin_inff(); int ni = 0x7FFFFFFF;
        for (int j=0;j<32;j++){
          float vv = dw[j*64 + lane]; int m = j*64 + lane;
          if (better(lastv, lasti, vv, m) && better(vv, m, nv, ni)){ nv=vv; ni=m; }
        }
        v[0] = nv; id[0] = ni;
      }
    }
  }
  if (lane < KNN) idxT[((size_t)b*KNN + lane)*N + nq] = win;
}

// ==================== register-tiled edge kernels ====================

// ---- edgeA (t-path): 3ch -> 64 -> 128, max over k ----
// v2: 4 waves x 16 points; stage2 tiled as 4 panels o=p*32+oq*4 (conflict-free w2T reads).
__global__ __launch_bounds__(256) void edgeA_kernel(
    const float* __restrict__ x, const int* __restrict__ idxT,
    const float* __restrict__ w1, const float* __restrict__ w2,
    float* __restrict__ tT, int N){
  __shared__ float w1aT[3*64];
  __shared__ float wd3T[3*64];
  __shared__ float w2T[64*128];      // [c][o]; reused as merge buffer (4 x 16r x 128o)
  __shared__ float aT3[4][3*16];
  __shared__ float s1T[4][64*16];    // [c][r]
  const int tid = threadIdx.x, w = tid>>6, lane = tid&63;
  const int oq = lane&7, rg = lane>>3;
  const int o0 = oq*8, r0 = rg*2;
  const int b = blockIdx.y, n0 = blockIdx.x*16;
  for (int i=tid; i<192; i+=256){
    int o = i&63, c = i/64;
    float a = w1[o*6+c];
    w1aT[c*64+o] = a; wd3T[c*64+o] = w1[o*6+3+c] - a;
  }
  for (int i=tid; i<128*64; i+=256){
    int o = i>>6, c = i&63;
    w2T[c*128+o] = w2[o*64+c];
  }
  if (tid < 48){ int c = tid>>4, r = tid&15; aT3[0][c*16+r] = x[((size_t)b*3+c)*N + n0 + r]; }
  __syncthreads();
  float base[16];
#pragma unroll
  for (int i=0;i<16;i++) base[i]=0.f;
#pragma unroll
  for (int c=0;c<3;c++){
    float4 wA = ld4(&wd3T[c*64+o0]), wB = ld4(&wd3T[c*64+o0+4]);
    float2 av = *(const float2*)&aT3[0][c*16+r0];
    float wv[8] = {wA.x,wA.y,wA.z,wA.w,wB.x,wB.y,wB.z,wB.w};
    float rv[2] = {av.x,av.y};
#pragma unroll
    for (int oo=0;oo<8;oo++)
#pragma unroll
      for (int rr=0;rr<2;rr++) base[oo*2+rr] = fmaf(wv[oo], rv[rr], base[oo*2+rr]);
  }
  __syncthreads();   // all waves done reading aT3[0] before k-loop overwrites
  float mx[32];
#pragma unroll
  for (int i=0;i<32;i++) mx[i] = -__builtin_inff();
  for (int it=0; it<10; it++){
    int k = it*4 + w;
    int m = idxT[((size_t)b*KNN + k)*N + n0 + (lane&15)];
    if (lane < 48){ int c = lane>>4; aT3[w][c*16 + (lane&15)] = x[((size_t)b*3+c)*N + m]; }
    // stage1 (64 o x 16 r)
    float acc[16];
#pragma unroll
    for (int i=0;i<16;i++) acc[i] = base[i];
#pragma unroll
    for (int c=0;c<3;c++){
      float4 wA = ld4(&w1aT[c*64+o0]), wB = ld4(&w1aT[c*64+o0+4]);
      float2 av = *(const float2*)&aT3[w][c*16+r0];
      float wv[8] = {wA.x,wA.y,wA.z,wA.w,wB.x,wB.y,wB.z,wB.w};
      float rv[2] = {av.x,av.y};
#pragma unroll
      for (int oo=0;oo<8;oo++)
#pragma unroll
        for (int rr=0;rr<2;rr++) acc[oo*2+rr] = fmaf(wv[oo], rv[rr], acc[oo*2+rr]);
    }
#pragma unroll
    for (int oo=0;oo<8;oo++){
      float2 sv; sv.x = lrelu(acc[oo*2]); sv.y = lrelu(acc[oo*2+1]);
      *(float2*)&s1T[w][(o0+oo)*16 + r0] = sv;
    }
    // stage2 (128 o x 16 r): 4 panels, o = p*32 + oq*4 -> 32 banks, conflict-free
    float acc2[32];
#pragma unroll
    for (int i=0;i<32;i++) acc2[i]=0.f;
    for (int c=0;c<64;c++){
      float2 av = *(const float2*)&s1T[w][c*16 + r0];
#pragma unroll
      for (int p=0;p<4;p++){
        float4 wv = ld4(&w2T[c*128 + p*32 + oq*4]);
        acc2[p*8+0] = fmaf(wv.x, av.x, acc2[p*8+0]);
        acc2[p*8+1] = fmaf(wv.x, av.y, acc2[p*8+1]);
        acc2[p*8+2] = fmaf(wv.y, av.x, acc2[p*8+2]);
        acc2[p*8+3] = fmaf(wv.y, av.y, acc2[p*8+3]);
        acc2[p*8+4] = fmaf(wv.z, av.x, acc2[p*8+4]);
        acc2[p*8+5] = fmaf(wv.z, av.y, acc2[p*8+5]);
        acc2[p*8+6] = fmaf(wv.w, av.x, acc2[p*8+6]);
        acc2[p*8+7] = fmaf(wv.w, av.y, acc2[p*8+7]);
      }
    }
#pragma unroll
    for (int i=0;i<32;i++) mx[i] = fmaxf(mx[i], lrelu(acc2[i]));
  }
  __syncthreads();   // all waves done reading w2T -> reuse as merge buffer
#pragma unroll
  for (int rr=0;rr<2;rr++){
#pragma unroll
    for (int p=0;p<4;p++){
      float4 a = make_float4(mx[p*8+0+rr], mx[p*8+2+rr], mx[p*8+4+rr], mx[p*8+6+rr]);
      *(float4*)&w2T[w*2048 + (r0+rr)*128 + p*32 + oq*4] = a;
    }
  }
  __syncthreads();
  for (int i=tid; i<2048; i+=256){
    float vv = fmaxf(fmaxf(w2T[i], w2T[2048+i]), fmaxf(w2T[4096+i], w2T[6144+i]));
    int r = i>>7, o = i&127;
    tT[((size_t)b*N + n0 + r)*128 + o] = vv;
  }
}

// ---- edgeB: 3ch -> 64 -> 64, max over k ----
__global__ __launch_bounds__(128) void edgeB_kernel(
    const float* __restrict__ xp, const int* __restrict__ idxT,
    const float* __restrict__ w1, const float* __restrict__ w2,
    float* __restrict__ catT, int N){
  __shared__ float w1aT[3*64];
  __shared__ float wd3T[3*64];
  __shared__ float w2T[64*64];
  __shared__ float aT3[2][3*32];
  __shared__ float s1T[2][64*32];
  const int tid = threadIdx.x, w = tid>>6, lane = tid&63;
  const int oq = lane&7, rg = lane>>3;
  const int o0 = oq*8, r0 = rg*4;
  const int b = blockIdx.y, n0 = blockIdx.x*32;
  for (int i=tid; i<192; i+=128){
    int o = i&63, c = i>>6;
    float a = w1[o*6+c], bb = w1[o*6+3+c];
    w1aT[c*64+o] = a; wd3T[c*64+o] = bb - a;
  }
  for (int i=tid; i<64*64; i+=128){
    int o = i>>6, c = i&63;
    w2T[c*64+o] = w2[o*64+c];
  }
  if (tid < 32){
#pragma unroll
    for (int c=0;c<3;c++) aT3[0][c*32+tid] = xp[((size_t)b*3+c)*N + n0 + tid];
  }
  __syncthreads();
  float base[32];
#pragma unroll
  for (int i=0;i<32;i++) base[i]=0.f;
#pragma unroll
  for (int c=0;c<3;c++){
    float4 w0 = ld4(&wd3T[c*64+o0]), w1v = ld4(&wd3T[c*64+o0+4]);
    float4 av = ld4(&aT3[0][c*32+r0]);
    float wv[8] = {w0.x,w0.y,w0.z,w0.w,w1v.x,w1v.y,w1v.z,w1v.w};
    float rv[4] = {av.x,av.y,av.z,av.w};
#pragma unroll
    for (int oo=0;oo<8;oo++)
#pragma unroll
      for (int rr=0;rr<4;rr++) base[oo*4+rr] = fmaf(wv[oo], rv[rr], base[oo*4+rr]);
  }
  __syncthreads();
  float mx[32];
#pragma unroll
  for (int i=0;i<32;i++) mx[i] = -__builtin_inff();
  for (int it=0; it<20; it++){
    int k = it*2 + w;
    {
      int row = lane&31;
      int m = idxT[((size_t)b*KNN + k)*N + n0 + row];
      if (lane < 32){
#pragma unroll
        for (int c=0;c<3;c++) aT3[w][c*32+row] = xp[((size_t)b*3+c)*N + m];
      }
    }
    float acc[32];
#pragma unroll
    for (int i=0;i<32;i++) acc[i] = base[i];
#pragma unroll
    for (int c=0;c<3;c++){
      float4 w0 = ld4(&w1aT[c*64+o0]), w1v = ld4(&w1aT[c*64+o0+4]);
      float4 av = ld4(&aT3[w][c*32+r0]);
      float wv[8] = {w0.x,w0.y,w0.z,w0.w,w1v.x,w1v.y,w1v.z,w1v.w};
      float rv[4] = {av.x,av.y,av.z,av.w};
#pragma unroll
      for (int oo=0;oo<8;oo++)
#pragma unroll
        for (int rr=0;rr<4;rr++) acc[oo*4+rr] = fmaf(wv[oo], rv[rr], acc[oo*4+rr]);
    }
#pragma unroll
    for (int oo=0;oo<8;oo++){
      float4 sv = make_float4(lrelu(acc[oo*4+0]), lrelu(acc[oo*4+1]), lrelu(acc[oo*4+2]), lrelu(acc[oo*4+3]));
      *(float4*)&s1T[w][(o0+oo)*32 + r0] = sv;
    }
    float acc2[32];
#pragma unroll
    for (int i=0;i<32;i++) acc2[i]=0.f;
    for (int c=0;c<64;c++){
      float4 w0 = ld4(&w2T[c*64+o0]), w1v = ld4(&w2T[c*64+o0+4]);
      float4 av = ld4(&s1T[w][c*32+r0]);
      float wv[8] = {w0.x,w0.y,w0.z,w0.w,w1v.x,w1v.y,w1v.z,w1v.w};
      float rv[4] = {av.x,av.y,av.z,av.w};
#pragma unroll
      for (int oo=0;oo<8;oo++)
#pragma unroll
        for (int rr=0;rr<4;rr++) acc2[oo*4+rr] = fmaf(wv[oo], rv[rr], acc2[oo*4+rr]);
    }
#pragma unroll
    for (int i=0;i<32;i++) mx[i] = fmaxf(mx[i], lrelu(acc2[i]));
  }
  __syncthreads();
#pragma unroll
  for (int rr=0;rr<4;rr++){
    float4 a = make_float4(mx[0*4+rr], mx[1*4+rr], mx[2*4+rr], mx[3*4+rr]);
    float4 bq = make_float4(mx[4*4+rr], mx[5*4+rr], mx[6*4+rr], mx[7*4+rr]);
    *(float4*)&s1T[w][(r0+rr)*64 + o0] = a;
    *(float4*)&s1T[w][(r0+rr)*64 + o0 + 4] = bq;
  }
  __syncthreads();
  for (int i=tid; i<2048; i+=128){
    float v = fmaxf(s1T[0][i], s1T[1][i]);
    int r = i>>6, o = i&63;
    catT[((size_t)b*N + n0 + r)*192 + o] = v;
  }
}

// ---- edgeC: 64ch -> 64 -> 64, max over k ----
__global__ __launch_bounds__(128) void edgeC_kernel(
    const float* __restrict__ inT, int inOff, const int* __restrict__ idxT,
    const float* __restrict__ w1, const float* __restrict__ w2,
    float* __restrict__ catT, int outOff, int N){
  __shared__ float w1T[64*64];
  __shared__ float w2T[64*64];
  __shared__ float aT[2][64*32];
  __shared__ float s1T[2][64*32];
  const int tid = threadIdx.x, w = tid>>6, lane = tid&63;
  const int oq = lane&7, rg = lane>>3;
  const int o0 = oq*8, r0 = rg*4;
  const int b = blockIdx.y, n0 = blockIdx.x*32;
  for (int i=tid; i<64*64; i+=128){
    int o = i>>6, c = i&63;
    float a = w1[o*128+c], bb = w1[o*128+64+c];
    w1T[c*64+o] = a; w2T[c*64+o] = bb - a;
  }
  for (int i=tid; i<512; i+=128){
    int p = i>>4, cq = i&15;
    float4 v = ld4(&inT[((size_t)b*N + n0 + p)*192 + inOff + cq*4]);
    aT[0][(cq*4+0)*32+p] = v.x; aT[0][(cq*4+1)*32+p] = v.y;
    aT[0][(cq*4+2)*32+p] = v.z; aT[0][(cq*4+3)*32+p] = v.w;
  }
  __syncthreads();
  float base[32];
#pragma unroll
  for (int i=0;i<32;i++) base[i]=0.f;
  for (int c=0;c<64;c++){
    float4 w0 = ld4(&w2T[c*64+o0]), w1v = ld4(&w2T[c*64+o0+4]);
    float4 av = ld4(&aT[0][c*32+r0]);
    float wv[8] = {w0.x,w0.y,w0.z,w0.w,w1v.x,w1v.y,w1v.z,w1v.w};
    float rv[4] = {av.x,av.y,av.z,av.w};
#pragma unroll
    for (int oo=0;oo<8;oo++)
#pragma unroll
      for (int rr=0;rr<4;rr++) base[oo*4+rr] = fmaf(wv[oo], rv[rr], base[oo*4+rr]);
  }
  __syncthreads();
  for (int i=tid; i<64*64; i+=128){
    int o = i>>6, c = i&63;
    w2T[c*64+o] = w2[o*64+c];
  }
  __syncthreads();
  float mx[32];
#pragma unroll
  for (int i=0;i<32;i++) mx[i] = -__builtin_inff();
  const int row = lane&31, ch = lane>>5;
  for (int it=0; it<20; it++){
    int k = it*2 + w;
    {
      int m = idxT[((size_t)b*KNN + k)*N + n0 + row];
      const float* src = &inT[((size_t)b*N + m)*192 + inOff + ch*32];
      float4 g[8];
#pragma unroll
      for (int j=0;j<8;j++) g[j] = ld4(src + j*4);
#pragma unroll
      for (int j=0;j<8;j++){
        aT[w][(ch*32+j*4+0)*32 + row] = g[j].x;
        aT[w][(ch*32+j*4+1)*32 + row] = g[j].y;
        aT[w][(ch*32+j*4+2)*32 + row] = g[j].z;
        aT[w][(ch*32+j*4+3)*32 + row] = g[j].w;
      }
    }
    float acc[32];
#pragma unroll
    for (int i=0;i<32;i++) acc[i] = base[i];
    for (int c=0;c<64;c++){
      float4 w0 = ld4(&w1T[c*64+o0]), w1v = ld4(&w1T[c*64+o0+4]);
      float4 av = ld4(&aT[w][c*32+r0]);
      float wv[8] = {w0.x,w0.y,w0.z,w0.w,w1v.x,w1v.y,w1v.z,w1v.w};
      float rv[4] = {av.x,av.y,av.z,av.w};
#pragma unroll
      for (int oo=0;oo<8;oo++)
#pragma unroll
        for (int rr=0;rr<4;rr++) acc[oo*4+rr] = fmaf(wv[oo], rv[rr], acc[oo*4+rr]);
    }
#pragma unroll
    for (int oo=0;oo<8;oo++){
      float4 sv = make_float4(lrelu(acc[oo*4+0]), lrelu(acc[oo*4+1]), lrelu(acc[oo*4+2]), lrelu(acc[oo*4+3]));
      *(float4*)&s1T[w][(o0+oo)*32 + r0] = sv;
    }
    float acc2[32];
#pragma unroll
    for (int i=0;i<32;i++) acc2[i]=0.f;
    for (int c=0;c<64;c++){
      float4 w0 = ld4(&w2T[c*64+o0]), w1v = ld4(&w2T[c*64+o0+4]);
      float4 av = ld4(&s1T[w][c*32+r0]);
      float wv[8] = {w0.x,w0.y,w0.z,w0.w,w1v.x,w1v.y,w1v.z,w1v.w};
      float rv[4] = {av.x,av.y,av.z,av.w};
#pragma unroll
      for (int oo=0;oo<8;oo++)
#pragma unroll
        for (int rr=0;rr<4;rr++) acc2[oo*4+rr] = fmaf(wv[oo], rv[rr], acc2[oo*4+rr]);
    }
#pragma unroll
    for (int i=0;i<32;i++) mx[i] = fmaxf(mx[i], lrelu(acc2[i]));
  }
  __syncthreads();
#pragma unroll
  for (int rr=0;rr<4;rr++){
    float4 a = make_float4(mx[0*4+rr], mx[1*4+rr], mx[2*4+rr], mx[3*4+rr]);
    float4 bq = make_float4(mx[4*4+rr], mx[5*4+rr], mx[6*4+rr], mx[7*4+rr]);
    *(float4*)&s1T[w][(r0+rr)*64 + o0] = a;
    *(float4*)&s1T[w][(r0+rr)*64 + o0 + 4] = bq;
  }
  __syncthreads();
  for (int i=tid; i<2048; i+=128){
    float v = fmaxf(s1T[0][i], s1T[1][i]);
    int r = i>>6, o = i&63;
    catT[((size_t)b*N + n0 + r)*192 + outOff + o] = v;
  }
}

// ---- edgeD: 64ch -> 64 (single conv), max over k ----
__global__ __launch_bounds__(128) void edgeD_kernel(
    const float* __restrict__ inT, int inOff, const int* __restrict__ idxT,
    const float* __restrict__ w1, float* __restrict__ catT, int outOff, int N){
  __shared__ float w1T[64*64];
  __shared__ float wdT[64*64];
  __shared__ float aT[2][64*32];
  const int tid = threadIdx.x, w = tid>>6, lane = tid&63;
  const int oq = lane&7, rg = lane>>3;
  const int o0 = oq*8, r0 = rg*4;
  const int b = blockIdx.y, n0 = blockIdx.x*32;
  for (int i=tid; i<64*64; i+=128){
    int o = i>>6, c = i&63;
    float a = w1[o*128+c], bb = w1[o*128+64+c];
    w1T[c*64+o] = a; wdT[c*64+o] = bb - a;
  }
  for (int i=tid; i<512; i+=128){
    int p = i>>4, cq = i&15;
    float4 v = ld4(&inT[((size_t)b*N + n0 + p)*192 + inOff + cq*4]);
    aT[0][(cq*4+0)*32+p] = v.x; aT[0][(cq*4+1)*32+p] = v.y;
    aT[0][(cq*4+2)*32+p] = v.z; aT[0][(cq*4+3)*32+p] = v.w;
  }
  __syncthreads();
  float base[32];
#pragma unroll
  for (int i=0;i<32;i++) base[i]=0.f;
  for (int c=0;c<64;c++){
    float4 w0 = ld4(&wdT[c*64+o0]), w1v = ld4(&wdT[c*64+o0+4]);
    float4 av = ld4(&aT[0][c*32+r0]);
    float wv[8] = {w0.x,w0.y,w0.z,w0.w,w1v.x,w1v.y,w1v.z,w1v.w};
    float rv[4] = {av.x,av.y,av.z,av.w};
#pragma unroll
    for (int oo=0;oo<8;oo++)
#pragma unroll
      for (int rr=0;rr<4;rr++) base[oo*4+rr] = fmaf(wv[oo], rv[rr], base[oo*4+rr]);
  }
  __syncthreads();
  float mx[32];
#pragma unroll
  for (int i=0;i<32;i++) mx[i] = -__builtin_inff();
  const int row = lane&31, ch = lane>>5;
  for (int it=0; it<20; it++){
    int k = it*2 + w;
    {
      int m = idxT[((size_t)b*KNN + k)*N + n0 + row];
      const float* src = &inT[((size_t)b*N + m)*192 + inOff + ch*32];
      float4 g[8];
#pragma unroll
      for (int j=0;j<8;j++) g[j] = ld4(src + j*4);
#pragma unroll
      for (int j=0;j<8;j++){
        aT[w][(ch*32+j*4+0)*32 + row] = g[j].x;
        aT[w][(ch*32+j*4+1)*32 + row] = g[j].y;
        aT[w][(ch*32+j*4+2)*32 + row] = g[j].z;
        aT[w][(ch*32+j*4+3)*32 + row] = g[j].w;
      }
    }
    float acc[32];
#pragma unroll
    for (int i=0;i<32;i++) acc[i] = base[i];
    for (int c=0;c<64;c++){
      float4 w0 = ld4(&w1T[c*64+o0]), w1v = ld4(&w1T[c*64+o0+4]);
      float4 av = ld4(&aT[w][c*32+r0]);
      float wv[8] = {w0.x,w0.y,w0.z,w0.w,w1v.x,w1v.y,w1v.z,w1v.w};
      float rv[4] = {av.x,av.y,av.z,av.w};
#pragma unroll
      for (int oo=0;oo<8;oo++)
#pragma unroll
        for (int rr=0;rr<4;rr++) acc[oo*4+rr] = fmaf(wv[oo], rv[rr], acc[oo*4+rr]);
    }
#pragma unroll
    for (int i=0;i<32;i++) mx[i] = fmaxf(mx[i], lrelu(acc[i]));
  }
  __syncthreads();
#pragma unroll
  for (int rr=0;rr<4;rr++){
    float4 a = make_float4(mx[0*4+rr], mx[1*4+rr], mx[2*4+rr], mx[3*4+rr]);
    float4 bq = make_float4(mx[4*4+rr], mx[5*4+rr], mx[6*4+rr], mx[7*4+rr]);
    *(float4*)&wdT[w*2048 + (r0+rr)*64 + o0] = a;
    *(float4*)&wdT[w*2048 + (r0+rr)*64 + o0 + 4] = bq;
  }
  __syncthreads();
  for (int i=tid; i<2048; i+=128){
    float v = fmaxf(wdT[i], wdT[2048+i]);
    int r = i>>6, o = i&63;
    catT[((size_t)b*N + n0 + r)*192 + outOff + o] = v;
  }
}

// ---------------- conv1 (1024 outs) + lrelu + max -- register-tiled, weights in LDS ----------------
template<int CIN, int TAG>
__global__ __launch_bounds__(128) void convmax_kernel(
    const float* __restrict__ inT, const float* __restrict__ wT,
    float* __restrict__ partial, int N){
  __shared__ float wsh[CIN*64];
  __shared__ float ish[32*CIN];     // [c][32]
  const int tid = threadIdx.x, w = tid>>6, lane = tid&63;
  const int oq = lane&7, rg = lane>>3;
  const int o0 = oq*8, r0 = rg*4;
  const int b = blockIdx.z, oc = blockIdx.x, nt = blockIdx.y;
  for (int i=tid; i<CIN*64; i+=128){
    int c = i>>6, o = i&63;
    wsh[i] = wT[(size_t)c*1024 + oc*64 + o];
  }
  float mx[32];
#pragma unroll
  for (int i=0;i<32;i++) mx[i] = -__builtin_inff();
  const int nbase = nt*(N/8);
  for (int st=0; st<8; st++){
    __syncthreads();
    const float* src = inT + ((size_t)b*N + nbase + st*32)*CIN;
    for (int i=tid; i<32*(CIN/4); i+=128){
      int p = i/(CIN/4), cq = i%(CIN/4);
      float4 v = ld4(src + p*CIN + 4*cq);
      ish[(4*cq+0)*32+p]=v.x; ish[(4*cq+1)*32+p]=v.y;
      ish[(4*cq+2)*32+p]=v.z; ish[(4*cq+3)*32+p]=v.w;
    }
    __syncthreads();
    float acc[32];
#pragma unroll
    for (int i=0;i<32;i++) acc[i]=0.f;
    for (int c=0;c<CIN;c++){
      float4 w0 = ld4(&wsh[c*64+o0]), w1v = ld4(&wsh[c*64+o0+4]);
      float4 av = ld4(&ish[c*32+r0]);
      float wv[8] = {w0.x,w0.y,w0.z,w0.w,w1v.x,w1v.y,w1v.z,w1v.w};
      float rv[4] = {av.x,av.y,av.z,av.w};
#pragma unroll
      for (int oo=0;oo<8;oo++)
#pragma unroll
        for (int rr=0;rr<4;rr++) acc[oo*4+rr] = fmaf(wv[oo], rv[rr], acc[oo*4+rr]);
    }
#pragma unroll
    for (int i=0;i<32;i++) mx[i] = fmaxf(mx[i], lrelu(acc[i]));
  }
  float m8[8];
#pragma unroll
  for (int oo=0;oo<8;oo++)
    m8[oo] = fmaxf(fmaxf(mx[oo*4+0], mx[oo*4+1]), fmaxf(mx[oo*4+2], mx[oo*4+3]));
  __syncthreads();
  *(float4*)&ish[(w*8+rg)*64 + o0]     = make_float4(m8[0],m8[1],m8[2],m8[3]);
  *(float4*)&ish[(w*8+rg)*64 + o0 + 4] = make_float4(m8[4],m8[5],m8[6],m8[7]);
  __syncthreads();
  if (tid < 64){
    float v = -__builtin_inff();
#pragma unroll
    for (int g=0; g<16; g++) v = fmaxf(v, ish[g*64+tid]);
    partial[((size_t)b*8 + nt)*1024 + oc*64 + tid] = v;
  }
}

template<int TAG>
__global__ void reduce_max_kernel(const float* __restrict__ partial, float* __restrict__ out){
  int b = blockIdx.y; int o = blockIdx.x*256 + threadIdx.x;
  float v = -__builtin_inff();
  for (int s=0;s<8;s++) v = fmaxf(v, partial[((size_t)b*8 + s)*1024 + o]);
  out[(size_t)b*1024 + o] = v;
}

// ---------------- small FC ----------------
__global__ void fc_kernel(const float* __restrict__ in, const float* __restrict__ W,
                          const float* __restrict__ bias, float* __restrict__ out,
                          int CI, int O, int act){
  int b = blockIdx.x;
  __shared__ float insh[1024];
  for (int i=threadIdx.x;i<CI;i+=blockDim.x) insh[i]=in[(size_t)b*CI+i];
  __syncthreads();
  for (int o=threadIdx.x;o<O;o+=blockDim.x){
    float s = bias ? bias[o] : 0.f;
    for (int c=0;c<CI;c++) s = fmaf(W[(size_t)o*CI+c], insh[c], s);
    if (act) s = lrelu(s);
    out[(size_t)b*O+o]=s;
  }
}

// ---------------- x' = T^T x per batch ----------------
__global__ void transform_kernel(const float* __restrict__ x, const float* __restrict__ T9,
                                 float* __restrict__ xp, int N){
  int b = blockIdx.y; int n = blockIdx.x*256 + threadIdx.x;
  const float* t = T9 + (size_t)b*9;
  float x0=x[((size_t)b*3+0)*N+n], x1=x[((size_t)b*3+1)*N+n], x2=x[((size_t)b*3+2)*N+n];
#pragma unroll
  for (int i=0;i<3;i++)
    xp[((size_t)b*3+i)*N+n] = t[i]*x0 + t[3+i]*x1 + t[6+i]*x2;
}

// ---------------- bias1: n-invariant part of h1 ----------------
__global__ void bias1_kernel(const float* __restrict__ g, const float* __restrict__ lv,
                             const float* __restrict__ h1w, float* __restrict__ bias1){
  int b = blockIdx.x;
  __shared__ float insh[1088];
  for (int i=threadIdx.x;i<1088;i+=256) insh[i] = (i<1024)? g[(size_t)b*1024+i] : lv[(size_t)b*64 + (i-1024)];
  __syncthreads();
  int o = threadIdx.x;
  float s=0.f;
  for (int c=0;c<1088;c++) s = fmaf(h1w[(size_t)o*1280+c], insh[c], s);
  bias1[(size_t)b*256+o]=s;
}

// ---------------- head conv layers ----------------
template<int CI, int O, bool ACT>
__global__ __launch_bounds__(256) void conv1_kernel(
    const float* __restrict__ inT, const float* __restrict__ wT,
    const float* __restrict__ bias, float* __restrict__ outT, int N){
  const int b = blockIdx.y, n0 = blockIdx.x*32;
  __shared__ float insh[32*CI];
  const float* src = inT + ((size_t)b*N + n0)*CI;
  for (int i=threadIdx.x;i<32*CI;i+=256) insh[i] = src[i];
  __syncthreads();
  constexpr int NREP = 256/O;
  constexpr int NLOC = 32/NREP;
  const int o = threadIdx.x % O, rep = threadIdx.x / O;
  float acc[NLOC];
#pragma unroll
  for (int t=0;t<NLOC;t++) acc[t]=0.f;
  for (int c=0;c<CI;c++){
    float wv = wT[c*O + o];
#pragma unroll
    for (int t=0;t<NLOC;t++) acc[t] = fmaf(wv, insh[(t*NREP+rep)*CI + c], acc[t]);
  }
  float bv = bias ? bias[(size_t)b*O + o] : 0.f;
#pragma unroll
  for (int t=0;t<NLOC;t++){
    float s = acc[t] + bv;
    if (ACT) s = lrelu(s);
    outT[((size_t)b*N + n0 + t*NREP + rep)*O + o] = s;
  }
}

// ---------------- final layer: 128 -> 50, rows-layout output (B,50,N) ----------------
__global__ __launch_bounds__(256) void conv_out_kernel(
    const float* __restrict__ inT, const float* __restrict__ wT,
    float* __restrict__ out, int N){
  const int b = blockIdx.y, n0 = blockIdx.x*32;
  __shared__ float insh[32*129];
  const float* src = inT + ((size_t)b*N + n0)*128;
  for (int i=threadIdx.x;i<32*128;i+=256){ int nn=i>>7, c=i&127; insh[nn*129+c]=src[i]; }
  __syncthreads();
  const int nl = threadIdx.x & 31, og = threadIdx.x >> 5;
  float acc[7];
#pragma unroll
  for (int t=0;t<7;t++) acc[t]=0.f;
  for (int c=0;c<128;c++){
    float iv = insh[nl*129+c];
#pragma unroll
    for (int t=0;t<7;t++){
      int o = og + 8*t;
      float wv = (o<50)? wT[c*50+o] : 0.f;
      acc[t] = fmaf(wv, iv, acc[t]);
    }
  }
#pragma unroll
  for (int t=0;t<7;t++){
    int o = og + 8*t;
    if (o < 50) out[((size_t)b*50+o)*N + n0 + nl] = acc[t];
  }
}

extern "C" void kernel_launch(void* const* d_in, const int* in_sizes, int n_in,
                              void* d_out, int out_size, void* d_ws, size_t ws_size,
                              hipStream_t stream){
  const float* x    = (const float*)d_in[0];
  const float* l    = (const float*)d_in[1];
  const float* t_c1 = (const float*)d_in[2];
  const float* t_c2 = (const float*)d_in[3];
  const float* t_c3 = (const float*)d_in[4];
  const float* t_f1 = (const float*)d_in[5];
  const float* t_f2 = (const float*)d_in[6];
  const float* t_f3w= (const float*)d_in[7];
  const float* t_f3b= (const float*)d_in[8];
  const float* b1a  = (const float*)d_in[9];
  const float* b1b  = (const float*)d_in[10];
  const float* b2a  = (const float*)d_in[11];
  const float* b2b  = (const float*)d_in[12];
  const float* b3a  = (const float*)d_in[13];
  const float* m1   = (const float*)d_in[14];
  const float* m2   = (const float*)d_in[15];
  const float* h1   = (const float*)d_in[16];
  const float* h2   = (const float*)d_in[17];
  const float* h3   = (const float*)d_in[18];
  const float* h4   = (const float*)d_in[19];
  float* out = (float*)d_out;
  float* ws = (float*)d_ws;
  const int N = NPTS, B = BATCH;

  size_t off = 0;
  auto alloc = [&](size_t nf){ float* p = ws + off; off += nf; return p; };
  float* WT_TC3 = alloc((size_t)128*1024);
  float* WT_M1  = alloc((size_t)192*1024);
  float* WT_H1B = alloc((size_t)192*256);
  float* WT_H2  = alloc((size_t)256*256);
  float* WT_H3  = alloc((size_t)256*128);
  float* WT_H4  = alloc((size_t)128*64);
  int*   IDXT   = (int*)alloc((size_t)B*N*KNN);
  float* XX     = alloc((size_t)B*N);
  float* TT     = alloc((size_t)B*N*128);
  float* PARTIAL= alloc((size_t)B*8*1024);
  float* TG     = alloc((size_t)B*1024);
  float* T512   = alloc((size_t)B*512);
  float* T256   = alloc((size_t)B*256);
  float* T9     = alloc((size_t)B*16);
  float* XP     = alloc((size_t)B*3*N);
  float* CATT   = alloc((size_t)B*N*192);
  float* G      = alloc((size_t)B*1024);
  float* LV     = alloc((size_t)B*64);
  float* BIAS1  = alloc((size_t)B*256);
  float* H1T    = alloc((size_t)B*N*256);
  float* H2T    = alloc((size_t)B*N*256);
  float* H3T    = alloc((size_t)B*N*128);
  (void)ws_size; (void)in_sizes; (void)n_in; (void)out_size;

  dim3 blk(256);
  dim3 eblk(128);
  // weight transposes
  transpose_kernel<<<dim3((1024*128+255)/256), blk, 0, stream>>>(t_c3, WT_TC3, 1024,128,128,0);
  transpose_kernel<<<dim3((1024*192+255)/256), blk, 0, stream>>>(m1,  WT_M1, 1024,192,192,0);
  transpose_kernel<<<dim3((256*192+255)/256),  blk, 0, stream>>>(h1, WT_H1B, 256,192,1280,1088);
  transpose_kernel<<<dim3((256*256+255)/256),  blk, 0, stream>>>(h2, WT_H2, 256,256,256,0);
  transpose_kernel<<<dim3((128*256+255)/256),  blk, 0, stream>>>(h3, WT_H3, 128,256,256,0);
  transpose_kernel<<<dim3((50*128+255)/256),   blk, 0, stream>>>(h4, WT_H4, 50,128,128,0);

  // t-path
  norms_rows_kernel<0><<<dim3(N/256,B), blk, 0, stream>>>(x, XX, N);
  knn3_kernel<0><<<dim3(N/4,B), blk, 0, stream>>>(x, XX, IDXT, N);
  edgeA_kernel<<<dim3(N/16,B), blk, 0, stream>>>(x, IDXT, t_c1, t_c2, TT, N);
  convmax_kernel<128,0><<<dim3(16,8,B), eblk, 0, stream>>>(TT, WT_TC3, PARTIAL, N);
  reduce_max_kernel<0><<<dim3(4,B), blk, 0, stream>>>(PARTIAL, TG);
  fc_kernel<<<dim3(B), dim3(512), 0, stream>>>(TG, t_f1, nullptr, T512, 1024, 512, 1);
  fc_kernel<<<dim3(B), dim3(512), 0, stream>>>(T512, t_f2, nullptr, T256, 512, 256, 1);
  fc_kernel<<<dim3(B), dim3(512), 0, stream>>>(T256, t_f3w, t_f3b, T9, 256, 9, 0);
  transform_kernel<<<dim3(N/256,B), blk, 0, stream>>>(x, T9, XP, N);

  // edge block 1 (transformed points, 3ch)
  norms_rows_kernel<1><<<dim3(N/256,B), blk, 0, stream>>>(XP, XX, N);
  knn3_kernel<1><<<dim3(N/4,B), blk, 0, stream>>>(XP, XX, IDXT, N);
  edgeB_kernel<<<dim3(N/32,B), eblk, 0, stream>>>(XP, IDXT, b1a, b1b, CATT, N);

  // edge block 2 (x1 = CATT[...,0:64])
  norms_cl_kernel<0><<<dim3(N/256,B), blk, 0, stream>>>(CATT, 0, XX, N);
  knn64_kernel<0><<<dim3(N/4,B), blk, 0, stream>>>(CATT, 0, XX, IDXT, N);
  edgeC_kernel<<<dim3(N/32,B), eblk, 0, stream>>>(CATT, 0, IDXT, b2a, b2b, CATT, 64, N);

  // edge block 3 (x2 = CATT[...,64:128])
  norms_cl_kernel<1><<<dim3(N/256,B), blk, 0, stream>>>(CATT, 64, XX, N);
  knn64_kernel<1><<<dim3(N/4,B), blk, 0, stream>>>(CATT, 64, XX, IDXT, N);
  edgeD_kernel<<<dim3(N/32,B), eblk, 0, stream>>>(CATT, 64, IDXT, b3a, CATT, 128, N);

  // global feature + head
  convmax_kernel<192,1><<<dim3(16,8,B), eblk, 0, stream>>>(CATT, WT_M1, PARTIAL, N);
  reduce_max_kernel<1><<<dim3(4,B), blk, 0, stream>>>(PARTIAL, G);
  fc_kernel<<<dim3(B), dim3(512), 0, stream>>>(l, m2, nullptr, LV, 16, 64, 1);
  bias1_kernel<<<dim3(B), blk, 0, stream>>>(G, LV, h1, BIAS1);
  conv1_kernel<192,256,true><<<dim3(N/32,B), blk, 0, stream>>>(CATT, WT_H1B, BIAS1, H1T, N);
  conv1_kernel<256,256,true><<<dim3(N/32,B), blk, 0, stream>>>(H1T, WT_H2, nullptr, H2T, N);
  conv1_kernel<256,128,true><<<dim3(N/32,B), blk, 0, stream>>>(H2T, WT_H3, nullptr, H3T, N);
  conv_out_kernel<<<dim3(N/32,B), blk, 0, stream>>>(H3T, WT_H4, out, N);
}